// Round 2
// baseline (307.580 us; speedup 1.0000x reference)
//
#include <hip/hip_runtime.h>

#define NTOT 65536   // B * NPG
#define DIM  512
#define BGR  64
#define NPG  1024
#define DROPN 512    // NPG - ceil(0.5 * NPG)
#define DEG_BLOCKS 64      // one full-graph degree histogram block per graph
#define MV_BLOCKS 2048

typedef float vf4 __attribute__((ext_vector_type(4)));
typedef unsigned long long u64;

// ---- K1: blocks [0,64): per-graph FULL in-degree histogram (LDS) -> norm;
//      blocks [64,2112): p = X@W wave-per-row (BW-bound, ~134 MB X stream) ----
__global__ __launch_bounds__(256) void k1_matvec_deg(
        const float* __restrict__ X, const float* __restrict__ W,
        const int* __restrict__ dst,
        float* __restrict__ p, float* __restrict__ norm, int epg) {
    __shared__ int dl[NPG];
    if (blockIdx.x < DEG_BLOCKS) {
        const int g = blockIdx.x;                    // 0..63
        const int nbase = g * NPG;
        for (int i = threadIdx.x; i < NPG; i += 256) dl[i] = 0;
        __syncthreads();
        const int4* d4 = (const int4*)(dst + (size_t)g * epg);
        const int n4 = epg >> 2;
        for (int i = threadIdx.x; i < n4; i += 256) {
            int4 d = d4[i];
            atomicAdd(&dl[d.x - nbase], 1);
            atomicAdd(&dl[d.y - nbase], 1);
            atomicAdd(&dl[d.z - nbase], 1);
            atomicAdd(&dl[d.w - nbase], 1);
        }
        __syncthreads();
        for (int i = threadIdx.x; i < NPG; i += 256) {
            int d = dl[i];
            norm[nbase + i] = d > 0 ? rsqrtf((float)d) : 0.f;
        }
    } else {
        const int lane = threadIdx.x & 63;
        const int wid  = ((blockIdx.x - DEG_BLOCKS) * 256 + threadIdx.x) >> 6; // 0..8191
        const int nw   = (MV_BLOCKS * 256) >> 6;                               // 8192
        const vf4* wr = (const vf4*)W;
        const vf4 w0 = wr[lane], w1 = wr[lane + 64];
        for (int row = wid; row < NTOT; row += 2 * nw) {
            const int row2 = row + nw;                         // NTOT % (2*nw) == 0
            const vf4* xr0 = (const vf4*)(X + (size_t)row  * DIM);
            const vf4* xr1 = (const vf4*)(X + (size_t)row2 * DIM);
            vf4 a0 = xr0[lane], a1 = xr0[lane + 64];
            vf4 b0 = xr1[lane], b1 = xr1[lane + 64];
            vf4 m0 = a0 * w0 + a1 * w1;
            vf4 m1 = b0 * w0 + b1 * w1;
            float s0 = m0[0] + m0[1] + m0[2] + m0[3];
            float s1 = m1[0] + m1[1] + m1[2] + m1[3];
            #pragma unroll
            for (int off = 32; off > 0; off >>= 1) {
                s0 += __shfl_down(s0, off, 64);
                s1 += __shfl_down(s1, off, 64);
            }
            if (lane == 0) { p[row] = s0; p[row2] = s1; }
        }
    }
}

// ---- K2 (fused old K2+K3): one block per graph. LDS scatter-sum over ALL of
//      the graph's edges, then w = relu(agg*norm + bias), hybrid register
//      bitonic sort of 1024 (value,index) keys, write gate. No partials. ----
__global__ __launch_bounds__(1024) void k2_agg_topk(
        const int* __restrict__ src, const int* __restrict__ dst,
        const float* __restrict__ p, const float* __restrict__ norm,
        const float* __restrict__ bias, float* __restrict__ gate, int epg) {
    __shared__ float hl[NPG];
    __shared__ float al[NPG];
    __shared__ u64 sk[NPG];
    const int g = blockIdx.x;
    const int t = threadIdx.x;
    const int nbase = g * NPG;
    const float nrm = norm[nbase + t];
    hl[t] = p[nbase + t] * nrm;
    al[t] = 0.f;
    __syncthreads();
    const int4* s4 = (const int4*)(src + (size_t)g * epg);
    const int4* d4 = (const int4*)(dst + (size_t)g * epg);
    const int n4 = epg >> 2;                       // 8192 -> 8 iters/thread
    for (int i = t; i < n4; i += 1024) {
        int4 s = s4[i];
        int4 d = d4[i];
        atomicAdd(&al[d.x - nbase], hl[s.x - nbase]);
        atomicAdd(&al[d.y - nbase], hl[s.y - nbase]);
        atomicAdd(&al[d.z - nbase], hl[s.z - nbase]);
        atomicAdd(&al[d.w - nbase], hl[s.w - nbase]);
    }
    __syncthreads();
    float w = al[t] * nrm + bias[0];
    w = w > 0.f ? w : 0.f;                // relu; w>=0 -> float bits order-preserving
    u64 key = ((u64)__float_as_uint(w) << 32) | (unsigned int)t;
    // ascending bitonic sort of 1024 unique (value,index) keys == jnp stable argsort
    for (int k = 2; k <= NPG; k <<= 1) {
        const bool up = ((t & k) == 0);
        for (int j = k >> 1; j >= 64; j >>= 1) {      // cross-wave: LDS exchange
            sk[t] = key;
            __syncthreads();
            u64 partner = sk[t ^ j];
            __syncthreads();
            bool takeMin = (((t & j) == 0) == up);
            key = takeMin ? (key < partner ? key : partner)
                          : (key > partner ? key : partner);
        }
        for (int j = ((k >> 1) < 32 ? (k >> 1) : 32); j >= 1; j >>= 1) {  // in-wave
            u64 partner = (u64)__shfl_xor((long long)key, j, 64);
            bool takeMin = (((t & j) == 0) == up);
            key = takeMin ? (key < partner ? key : partner)
                          : (key > partner ? key : partner);
        }
    }
    int idx = (int)(key & 0xffffffffull);
    float wv = __uint_as_float((unsigned int)(key >> 32));
    gate[nbase + idx] = (t < DROPN) ? 0.f : wv;
}

// ---- K3: out[row,:] = X[row,:] * gate[row]; NT stores keep X L3-resident ----
__global__ __launch_bounds__(256) void k3_gate(
        const float* __restrict__ X, const float* __restrict__ gate,
        float* __restrict__ out) {
    const int lane = threadIdx.x & 63;
    const int nw   = (gridDim.x * blockDim.x) >> 6;
    const int wid  = (blockIdx.x * blockDim.x + threadIdx.x) >> 6;
    for (int row = wid; row < NTOT; row += nw) {
        float g = gate[row];
        vf4* o = (vf4*)(out + (size_t)row * DIM);
        if (g == 0.f) {                    // wave-uniform (whole wave = one row)
            vf4 z = (vf4){0.f, 0.f, 0.f, 0.f};
            __builtin_nontemporal_store(z, &o[lane]);
            __builtin_nontemporal_store(z, &o[lane + 64]);
        } else {
            const vf4* xr = (const vf4*)(X + (size_t)row * DIM);
            vf4 a = xr[lane] * g;
            vf4 c = xr[lane + 64] * g;
            __builtin_nontemporal_store(a, &o[lane]);
            __builtin_nontemporal_store(c, &o[lane + 64]);
        }
    }
}

extern "C" void kernel_launch(void* const* d_in, const int* in_sizes, int n_in,
                              void* d_out, int out_size, void* d_ws, size_t ws_size,
                              hipStream_t stream) {
    const float* X    = (const float*)d_in[0];
    const int*   src  = (const int*)d_in[1];
    const int*   dst  = (const int*)d_in[2];
    const float* W    = (const float*)d_in[3];
    const float* bias = (const float*)d_in[4];
    float* out = (float*)d_out;
    int E   = in_sizes[1];
    int epg = E / BGR;

    float* ws   = (float*)d_ws;
    float* p    = ws;                       // [N] f32
    float* norm = ws + 1 * NTOT;            // [N] f32
    float* gate = ws + 2 * NTOT;            // [N] f32

    k1_matvec_deg<<<DEG_BLOCKS + MV_BLOCKS, 256, 0, stream>>>(X, W, dst, p, norm, epg);
    k2_agg_topk<<<BGR, 1024, 0, stream>>>(src, dst, p, norm, bias, gate, epg);
    k3_gate<<<2048, 256, 0, stream>>>(X, gate, out);
}

// Round 3
// 276.933 us; speedup vs baseline: 1.1107x; 1.1107x over previous
//
#include <hip/hip_runtime.h>

#define NTOT 65536   // B * NPG
#define DIM  512
#define BGR  64
#define NPG  1024
#define DROPN 512    // NPG - ceil(0.5 * NPG)
#define SLICES 8     // edge slices per graph (K2 parallelism)
#define DEG_BLOCKS 64      // one full-graph degree histogram block per graph
#define MV_BLOCKS 2048

typedef float vf4 __attribute__((ext_vector_type(4)));
typedef unsigned long long u64;

// ---- K1: blocks [0,64): per-graph FULL in-degree histogram (LDS) -> norm;
//      blocks [64,2112): p = X@W wave-per-row (BW-bound, ~134 MB X stream) ----
__global__ __launch_bounds__(256) void k1_matvec_deg(
        const float* __restrict__ X, const float* __restrict__ W,
        const int* __restrict__ dst,
        float* __restrict__ p, float* __restrict__ norm, int epg) {
    __shared__ int dl[NPG];
    if (blockIdx.x < DEG_BLOCKS) {
        const int g = blockIdx.x;                    // 0..63
        const int nbase = g * NPG;
        for (int i = threadIdx.x; i < NPG; i += 256) dl[i] = 0;
        __syncthreads();
        const int4* d4 = (const int4*)(dst + (size_t)g * epg);
        const int n4 = epg >> 2;
        for (int i = threadIdx.x; i < n4; i += 256) {
            int4 d = d4[i];
            atomicAdd(&dl[d.x - nbase], 1);
            atomicAdd(&dl[d.y - nbase], 1);
            atomicAdd(&dl[d.z - nbase], 1);
            atomicAdd(&dl[d.w - nbase], 1);
        }
        __syncthreads();
        for (int i = threadIdx.x; i < NPG; i += 256) {
            int d = dl[i];
            norm[nbase + i] = d > 0 ? rsqrtf((float)d) : 0.f;
        }
    } else {
        const int lane = threadIdx.x & 63;
        const int wid  = ((blockIdx.x - DEG_BLOCKS) * 256 + threadIdx.x) >> 6; // 0..8191
        const int nw   = (MV_BLOCKS * 256) >> 6;                               // 8192
        const vf4* wr = (const vf4*)W;
        const vf4 w0 = wr[lane], w1 = wr[lane + 64];
        for (int row = wid; row < NTOT; row += 2 * nw) {
            const int row2 = row + nw;                         // NTOT % (2*nw) == 0
            const vf4* xr0 = (const vf4*)(X + (size_t)row  * DIM);
            const vf4* xr1 = (const vf4*)(X + (size_t)row2 * DIM);
            vf4 a0 = xr0[lane], a1 = xr0[lane + 64];
            vf4 b0 = xr1[lane], b1 = xr1[lane + 64];
            vf4 m0 = a0 * w0 + a1 * w1;
            vf4 m1 = b0 * w0 + b1 * w1;
            float s0 = m0[0] + m0[1] + m0[2] + m0[3];
            float s1 = m1[0] + m1[1] + m1[2] + m1[3];
            #pragma unroll
            for (int off = 32; off > 0; off >>= 1) {
                s0 += __shfl_down(s0, off, 64);
                s1 += __shfl_down(s1, off, 64);
            }
            if (lane == 0) { p[row] = s0; p[row2] = s1; }
        }
    }
}

// ---- K2: per (graph,slice): hn staged in LDS; LDS scatter-sum of slice edges;
//      write agg partial. 512 blocks -> whole machine busy on edge phase. ----
__global__ __launch_bounds__(256) void k2_agg(
        const int* __restrict__ src, const int* __restrict__ dst,
        const float* __restrict__ p, const float* __restrict__ norm,
        float* __restrict__ agg_part, int epg) {
    __shared__ float hl[NPG];
    __shared__ float al[NPG];
    const int b = blockIdx.x;
    const int g = b & (BGR - 1);
    const int slice = b >> 6;
    const int nbase = g * NPG;
    const int eps = epg / SLICES;
    for (int i = threadIdx.x; i < NPG; i += 256) {
        hl[i] = p[nbase + i] * norm[nbase + i];
        al[i] = 0.f;
    }
    __syncthreads();
    const int4* s4 = (const int4*)(src + (size_t)g * epg + (size_t)slice * eps);
    const int4* d4 = (const int4*)(dst + (size_t)g * epg + (size_t)slice * eps);
    const int n4 = eps >> 2;
    for (int i = threadIdx.x; i < n4; i += 256) {
        int4 s = s4[i];
        int4 d = d4[i];
        atomicAdd(&al[d.x - nbase], hl[s.x - nbase]);
        atomicAdd(&al[d.y - nbase], hl[s.y - nbase]);
        atomicAdd(&al[d.z - nbase], hl[s.z - nbase]);
        atomicAdd(&al[d.w - nbase], hl[s.w - nbase]);
    }
    __syncthreads();
    float* op = agg_part + (size_t)slice * NTOT + nbase;
    for (int i = threadIdx.x; i < NPG; i += 256) op[i] = al[i];
}

// ---- K3: per graph: w = relu(agg*norm + bias); 4-pass radix SELECT of the
//      rank-DROPN threshold (value bits), index tie-break identical to the
//      stable u64 sort: drop the kp lowest-index members of the equal set. ----
__global__ __launch_bounds__(1024) void k3_topk(
        const float* __restrict__ agg_part, const float* __restrict__ norm,
        const float* __restrict__ bias, float* __restrict__ gate) {
    __shared__ unsigned int hist[256];
    __shared__ unsigned int selbin, selkp;
    __shared__ unsigned int wsum[16];
    const int g = blockIdx.x;
    const int t = threadIdx.x;
    const int lane = t & 63;
    const int wid  = t >> 6;
    const int nbase = g * NPG;
    float a = 0.f;
    #pragma unroll
    for (int s = 0; s < SLICES; s++) a += agg_part[(size_t)s * NTOT + nbase + t];
    float w = a * norm[nbase + t] + bias[0];
    w = w > 0.f ? w : 0.f;                 // relu; w>=0 -> uint bits order-preserving
    const unsigned int v = __float_as_uint(w);
    bool act = true;                        // still matches threshold prefix
    unsigned int kp = DROPN;                // residual rank within active set
    unsigned int T = 0;                     // threshold value bits, built per pass
    #pragma unroll
    for (int shift = 24; shift >= 0; shift -= 8) {
        if (t < 256) hist[t] = 0;
        __syncthreads();
        const unsigned int byte = (v >> shift) & 255u;
        if (act) atomicAdd(&hist[byte], 1u);
        __syncthreads();
        if (t < 64) {                       // wave-0 inclusive scan, 4 bins/lane
            unsigned int h0 = hist[t*4], h1 = hist[t*4+1], h2 = hist[t*4+2], h3 = hist[t*4+3];
            unsigned int lsum = h0 + h1 + h2 + h3;
            unsigned int x = lsum;
            #pragma unroll
            for (int off = 1; off < 64; off <<= 1) {
                unsigned int y = (unsigned int)__shfl_up((int)x, off, 64);
                if (lane >= off) x += y;
            }
            unsigned int excl = x - lsum;
            hist[t*4]   = excl + h0;
            hist[t*4+1] = excl + h0 + h1;
            hist[t*4+2] = excl + h0 + h1 + h2;
            hist[t*4+3] = excl + h0 + h1 + h2 + h3;
        }
        __syncthreads();
        if (t < 256) {
            unsigned int lo = (t == 0) ? 0u : hist[t-1];
            unsigned int hi = hist[t];
            if (lo <= kp && kp < hi) { selbin = (unsigned int)t; selkp = kp - lo; }
        }
        __syncthreads();
        const unsigned int b = selbin;      // read before any thread can rewrite
        kp = selkp;                         // (two barriers before next sel write)
        act = act && (byte == b);
        T |= b << shift;
    }
    // act == (v == T); kp = DROPN - #(v < T) = drops remaining among equals
    u64 bal = __ballot(act);
    if (lane == 0) wsum[wid] = (unsigned int)__popcll(bal);
    __syncthreads();
    unsigned int wpre = 0;
    for (int i = 0; i < wid; i++) wpre += wsum[i];
    unsigned int eqrank = wpre + (unsigned int)__popcll(bal & ((1ull << lane) - 1ull));
    bool keep = act ? (eqrank >= kp) : (v > T);
    gate[nbase + t] = keep ? w : 0.f;
}

// ---- K4: out[row,:] = X[row,:] * gate[row]; NT stores keep X L3-resident ----
__global__ __launch_bounds__(256) void k4_gate(
        const float* __restrict__ X, const float* __restrict__ gate,
        float* __restrict__ out) {
    const int lane = threadIdx.x & 63;
    const int nw   = (gridDim.x * blockDim.x) >> 6;
    const int wid  = (blockIdx.x * blockDim.x + threadIdx.x) >> 6;
    for (int row = wid; row < NTOT; row += nw) {
        float g = gate[row];
        vf4* o = (vf4*)(out + (size_t)row * DIM);
        if (g == 0.f) {                    // wave-uniform (whole wave = one row)
            vf4 z = (vf4){0.f, 0.f, 0.f, 0.f};
            __builtin_nontemporal_store(z, &o[lane]);
            __builtin_nontemporal_store(z, &o[lane + 64]);
        } else {
            const vf4* xr = (const vf4*)(X + (size_t)row * DIM);
            vf4 a = xr[lane] * g;
            vf4 c = xr[lane + 64] * g;
            __builtin_nontemporal_store(a, &o[lane]);
            __builtin_nontemporal_store(c, &o[lane + 64]);
        }
    }
}

extern "C" void kernel_launch(void* const* d_in, const int* in_sizes, int n_in,
                              void* d_out, int out_size, void* d_ws, size_t ws_size,
                              hipStream_t stream) {
    const float* X    = (const float*)d_in[0];
    const int*   src  = (const int*)d_in[1];
    const int*   dst  = (const int*)d_in[2];
    const float* W    = (const float*)d_in[3];
    const float* bias = (const float*)d_in[4];
    float* out = (float*)d_out;
    int E   = in_sizes[1];
    int epg = E / BGR;

    float* ws       = (float*)d_ws;
    float* p        = ws;                       // [N] f32
    float* norm     = ws + 1 * NTOT;            // [N] f32
    float* gate     = ws + 2 * NTOT;            // [N] f32
    float* agg_part = ws + 3 * NTOT;            // [SLICES][N] f32

    k1_matvec_deg<<<DEG_BLOCKS + MV_BLOCKS, 256, 0, stream>>>(X, W, dst, p, norm, epg);
    k2_agg<<<BGR * SLICES, 256, 0, stream>>>(src, dst, p, norm, agg_part, epg);
    k3_topk<<<BGR, 1024, 0, stream>>>(agg_part, norm, bias, gate);
    k4_gate<<<2048, 256, 0, stream>>>(X, gate, out);
}